// Round 1
// baseline (42.521 us; speedup 1.0000x reference)
//
#include <hip/hip_runtime.h>

#define N  2048
#define K  8
#define NK 1024
#define TAU_C 0.5f
#define TAU_S 0.5f

// pos[k*N + x] = position of node x in client k's index list, or -1 if absent.
__global__ void fia_build_pos(const int* __restrict__ idx, int* __restrict__ pos) {
    int t = blockIdx.x * blockDim.x + threadIdx.x;
    if (t < K * NK) {
        int k = t >> 10;          // t / NK
        int p = t & (NK - 1);     // t % NK
        int x = idx[t];
        pos[k * N + x] = p;
    }
}

__global__ void fia_main(const float* __restrict__ adj,
                         const int* __restrict__ pos,
                         float* __restrict__ out) {
    int y = blockIdx.x * blockDim.x + threadIdx.x;  // column, 0..N-1
    int x = blockIdx.y;                              // row
    if (y >= N) return;

    float vals[K];
    int   mbits = 0;
    float sum = 0.f, cnt = 0.f;

    #pragma unroll
    for (int k = 0; k < K; ++k) {
        int i = pos[k * N + x];   // block-uniform -> L1 broadcast
        int j = pos[k * N + y];   // coalesced across lanes
        bool present = ((i | j) >= 0);   // both sign bits clear
        float a = 0.f;
        if (present) {
            a = adj[((size_t)k * NK + (size_t)i) * NK + (size_t)j];
        }
        vals[k] = a;
        mbits |= (present ? 1 : 0) << k;
        sum += a;                          // absent adds exact 0.0f, matches ref
        cnt += present ? 1.f : 0.f;
    }

    float num_obs = fmaxf(cnt, 1e-5f);
    float mean    = sum / num_obs;         // IEEE f32 divide, matches ref

    float csum = 0.f, vsum = 0.f;
    #pragma unroll
    for (int k = 0; k < K; ++k) {
        bool  p = (mbits >> k) & 1;
        float a = vals[k];
        csum += (p && (a > TAU_C)) ? 1.f : 0.f;
        float d = a - mean;
        vsum += p ? d * d : 0.f;           // mask multiplies out absent terms
    }

    float C = csum / num_obs;
    float V = vsum / num_obs;
    float S = C * expf(-V);                // precise expf, NOT __expf
    float r = (S > TAU_S) ? mean : 0.f;
    r = (cnt > 0.f) ? r : 0.f;             // (num_obs > 1e-5) gate

    out[(size_t)x * N + y] = r;
}

extern "C" void kernel_launch(void* const* d_in, const int* in_sizes, int n_in,
                              void* d_out, int out_size, void* d_ws, size_t ws_size,
                              hipStream_t stream) {
    const float* adj = (const float*)d_in[0];   // (K, NK, NK) f32
    const int*   idx = (const int*)d_in[1];     // (K, NK) i32
    float*       out = (float*)d_out;           // (N, N) f32
    int*         pos = (int*)d_ws;              // K*N ints = 64 KB

    // pos = -1 everywhere
    hipMemsetAsync(pos, 0xFF, (size_t)K * N * sizeof(int), stream);

    // scatter positions
    {
        int total = K * NK;
        int block = 256;
        int grid  = (total + block - 1) / block;
        fia_build_pos<<<grid, block, 0, stream>>>(idx, pos);
    }

    // main: one thread per output element
    {
        dim3 block(256, 1, 1);
        dim3 grid(N / 256, N, 1);
        fia_main<<<grid, block, 0, stream>>>(adj, pos, out);
    }
}